// Round 1
// baseline (7171.297 us; speedup 1.0000x reference)
//
#include <hip/hip_runtime.h>

// Conv2dODENet: adaptive dopri5 (32 bounded iters) over a 3-conv ODE func, fp32 mirror.
// B=8 H=64 W=64 C=64 F=128 OUT=10, TOL=1e-3, H0=0.1
#define NYF   2097152   // 8*64*64*64 (y elements)
#define NPIXT 32768     // 8*64*64

struct Scal {
  double errsum;
  float t, h, hs;
  int done, accept, is_bf16;
};

static __device__ __forceinline__ float bf2f(unsigned short u) {
  return __uint_as_float(((unsigned)u) << 16);
}
static __device__ __forceinline__ unsigned short f2bf(float f) {
  unsigned u = __float_as_uint(f);
  u += 0x7FFFu + ((u >> 16) & 1u);   // round-to-nearest-even
  return (unsigned short)(u >> 16);
}

// ---- dtype detection + scalar-state init (runs every call) -----------------
__global__ void detect_kernel(Scal* scal, const void* x) {
  if (threadIdx.x == 0 && blockIdx.x == 0) {
    const unsigned short* u = (const unsigned short*)x;
    int cnt = 0;
    for (int i = 0; i < 256; i++) {
      int e = (u[2 * i] >> 7) & 0xFF;      // exp field of LOW half of each 32-bit word
      if (e >= 100 && e <= 140) cnt++;     // bf16 N(0,1) data: ~all in range; f32 mantissa: ~16%
    }
    scal->is_bf16 = (cnt >= 200);
    scal->t = 0.0f; scal->h = 0.1f;
    scal->done = 0; scal->accept = 0; scal->errsum = 0.0;
  }
}

__global__ __launch_bounds__(256) void convert_x_kernel(const Scal* __restrict__ scal,
    const void* __restrict__ x, float* __restrict__ y) {
  int i = blockIdx.x * 256 + threadIdx.x;   // float4 units, NYF/4 total
  float4 v;
  if (scal->is_bf16) {
    ushort4 u = ((const ushort4*)x)[i];
    v.x = bf2f(u.x); v.y = bf2f(u.y); v.z = bf2f(u.z); v.w = bf2f(u.w);
  } else {
    v = ((const float4*)x)[i];
  }
  ((float4*)y)[i] = v;
}

// Pack all weights/biases (upcast to f32) contiguously into wbuf.
__global__ __launch_bounds__(256) void convert_w_kernel(const Scal* __restrict__ scal,
    const void* s0, const void* s1, const void* s2, const void* s3,
    const void* s4, const void* s5, const void* s6, const void* s7,
    float* __restrict__ wbuf) {
  const void* srcs[8] = {s0, s1, s2, s3, s4, s5, s6, s7};
  const int cum[9] = {0, 8320, 8448, 157056, 157184, 165440, 165504, 166144, 166154};
  int idx = blockIdx.x * 256 + threadIdx.x;
  if (idx >= 166154) return;
  int seg = 0;
  while (idx >= cum[seg + 1]) seg++;
  int local = idx - cum[seg];
  float v = scal->is_bf16 ? bf2f(((const unsigned short*)srcs[seg])[local])
                          : ((const float*)srcs[seg])[local];
  wbuf[idx] = v;
}

// ---- dopri5 scalar control --------------------------------------------------
__global__ void prep_kernel(Scal* scal) {
  float t = scal->t, h = scal->h;
  int done = (t >= 1.0f) ? 1 : 0;
  float hs = fminf(h, 1.0f - t);
  scal->hs = hs; scal->done = done;
  scal->accept = 0; scal->errsum = 0.0;
}

__global__ void accept_kernel(Scal* scal) {
  int done = scal->done;
  float hs = scal->hs;
  float en = sqrtf((float)(scal->errsum / (double)NYF));
  int accept = (en <= 1.0f && !done) ? 1 : 0;
  scal->accept = accept;
  if (accept) scal->t = scal->t + hs;
  if (!done) {
    float en_s = fmaxf(en, 1e-8f);
    float fac = 0.9f * powf(en_s, -0.2f);
    fac = fminf(fmaxf(fac, 0.2f), 10.0f);
    scal->h = fmaxf(hs * fac, 1e-4f);
  }
}

// ---- stage-input combination: out = y + hs * (c0*k0 + ... ) -----------------
template<int NK>
__global__ __launch_bounds__(256) void axpy_kernel(const Scal* __restrict__ scal,
    const float* __restrict__ y, float* __restrict__ out,
    const float* __restrict__ k0, const float* __restrict__ k1,
    const float* __restrict__ k2, const float* __restrict__ k3,
    const float* __restrict__ k4,
    float c0, float c1, float c2, float c3, float c4) {
  if (scal->done) return;
  const float hs = scal->hs;
  int i = blockIdx.x * 256 + threadIdx.x;
  float4 yv = ((const float4*)y)[i];
  float4 v = ((const float4*)k0)[i];
  float sx = c0 * v.x, sy = c0 * v.y, sz = c0 * v.z, sw = c0 * v.w;
  if constexpr (NK > 1) { float4 q = ((const float4*)k1)[i]; sx += c1*q.x; sy += c1*q.y; sz += c1*q.z; sw += c1*q.w; }
  if constexpr (NK > 2) { float4 q = ((const float4*)k2)[i]; sx += c2*q.x; sy += c2*q.y; sz += c2*q.z; sw += c2*q.w; }
  if constexpr (NK > 3) { float4 q = ((const float4*)k3)[i]; sx += c3*q.x; sy += c3*q.y; sz += c3*q.z; sw += c3*q.w; }
  if constexpr (NK > 4) { float4 q = ((const float4*)k4)[i]; sx += c4*q.x; sy += c4*q.y; sz += c4*q.z; sw += c4*q.w; }
  float4 o;
  o.x = yv.x + hs * sx; o.y = yv.y + hs * sy; o.z = yv.z + hs * sz; o.w = yv.w + hs * sw;
  ((float4*)out)[i] = o;
}

// ---- 1x1 conv (GEMM), time channel folded analytically ----------------------
// w layout: [(KIN+1)][NOUT], row 0 = time-channel weights.
template<int KIN, int NOUT, int CPT, int NT, bool RELU>
__global__ __launch_bounds__(NT) void conv1x1_kernel(const Scal* __restrict__ scal, float cs,
    const float* __restrict__ in, const float* __restrict__ w,
    const float* __restrict__ bias, float* __restrict__ out) {
  if (scal->done) return;
  constexpr int NCG = NOUT / CPT;     // cout groups
  constexpr int NPG = NT / NCG;       // pixel groups (4 px each)
  constexpr int PIX = NPG * 4;
  constexpr int RS = KIN + 4;         // pad to break bank conflicts, keeps 16B align
  __shared__ float in_lds[PIX * RS];
  __shared__ float w_lds[(KIN + 1) * NOUT];
  const int tid = threadIdx.x;
  const int cg = tid % NCG;
  const int pg = tid / NCG;
  const int pix0 = blockIdx.x * PIX;
  const float ts = scal->t + cs * scal->hs;

  for (int idx = tid; idx < (KIN + 1) * NOUT / 4; idx += NT)
    ((float4*)w_lds)[idx] = ((const float4*)w)[idx];
  const float4* inb = (const float4*)(in + (size_t)pix0 * KIN);
  for (int idx = tid; idx < PIX * KIN / 4; idx += NT) {
    int p = idx / (KIN / 4);
    int c4 = (idx % (KIN / 4)) * 4;
    *(float4*)&in_lds[p * RS + c4] = inb[idx];
  }
  __syncthreads();

  const int co0 = cg * CPT;
  float acc[4][CPT];
  #pragma unroll
  for (int j4 = 0; j4 < CPT / 4; j4++) {
    float4 bv = *(const float4*)&bias[co0 + j4 * 4];
    float4 wt = *(const float4*)&w_lds[co0 + j4 * 4];   // time row
    float i0 = bv.x + ts * wt.x, i1 = bv.y + ts * wt.y;
    float i2 = bv.z + ts * wt.z, i3 = bv.w + ts * wt.w;
    #pragma unroll
    for (int p = 0; p < 4; p++) {
      acc[p][j4*4+0] = i0; acc[p][j4*4+1] = i1;
      acc[p][j4*4+2] = i2; acc[p][j4*4+3] = i3;
    }
  }
  const int ib = (pg * 4) * RS;
  #pragma unroll 4
  for (int k4 = 0; k4 < KIN / 4; k4++) {
    float4 av[4];
    #pragma unroll
    for (int p = 0; p < 4; p++)
      av[p] = *(const float4*)&in_lds[ib + p * RS + k4 * 4];
    #pragma unroll
    for (int j = 0; j < 4; j++) {
      #pragma unroll
      for (int j4 = 0; j4 < CPT / 4; j4++) {
        float4 wv = *(const float4*)&w_lds[(1 + k4 * 4 + j) * NOUT + co0 + j4 * 4];
        #pragma unroll
        for (int p = 0; p < 4; p++) {
          float a = ((const float*)&av[p])[j];
          acc[p][j4*4+0] += a * wv.x; acc[p][j4*4+1] += a * wv.y;
          acc[p][j4*4+2] += a * wv.z; acc[p][j4*4+3] += a * wv.w;
        }
      }
    }
  }
  #pragma unroll
  for (int p = 0; p < 4; p++) {
    size_t ob = (size_t)(pix0 + pg * 4 + p) * NOUT + co0;
    #pragma unroll
    for (int j4 = 0; j4 < CPT / 4; j4++) {
      float4 v;
      v.x = acc[p][j4*4+0]; v.y = acc[p][j4*4+1];
      v.z = acc[p][j4*4+2]; v.w = acc[p][j4*4+3];
      if (RELU) { v.x = fmaxf(v.x, 0.f); v.y = fmaxf(v.y, 0.f); v.z = fmaxf(v.z, 0.f); v.w = fmaxf(v.w, 0.f); }
      *(float4*)&out[ob + j4 * 4] = v;
    }
  }
}

// ---- 3x3 SAME conv, 129(in incl. time)->128, relu ---------------------------
// w layout: [9][129][128], cin row 0 = time channel.
__global__ __launch_bounds__(256) void conv3x3_kernel(const Scal* __restrict__ scal, float cs,
    const float* __restrict__ in, const float* __restrict__ w,
    const float* __restrict__ bias, float* __restrict__ out) {
  if (scal->done) return;
  __shared__ float in_lds[100 * 132];    // 10x10 halo tile, RS=132 (52.8 KB)
  __shared__ float w_lds[16 * 128];      // 16-cin weight chunk (8 KB)
  const int tid = threadIdx.x;
  const int b = blockIdx.x >> 6;
  const int tile = blockIdx.x & 63;
  const int ty0 = (tile >> 3) << 3;
  const int tx0 = (tile & 7) << 3;
  const float ts = scal->t + cs * scal->hs;

  for (int idx = tid; idx < 3200; idx += 256) {     // 100 pos x 32 float4
    int pos = idx >> 5, c4 = (idx & 31) << 2;
    int iy = pos / 10, ix = pos - iy * 10;
    int gy = ty0 + iy - 1, gx = tx0 + ix - 1;
    float4 v = make_float4(0.f, 0.f, 0.f, 0.f);
    if (gy >= 0 && gy < 64 && gx >= 0 && gx < 64)
      v = *(const float4*)&in[(((size_t)(b * 64 + gy)) * 64 + gx) * 128 + c4];
    *(float4*)&in_lds[pos * 132 + c4] = v;
  }

  const int cg = tid & 15;       // 16 cout groups x 8 couts
  const int pg = tid >> 4;       // 16 pixel groups x 4 px
  const int py = pg >> 1;
  const int px0 = (pg & 1) << 2;
  const int co0 = cg << 3;
  float acc[4][8];
  {
    float4 b0 = *(const float4*)&bias[co0];
    float4 b1 = *(const float4*)&bias[co0 + 4];
    #pragma unroll
    for (int p = 0; p < 4; p++) {
      acc[p][0] = b0.x; acc[p][1] = b0.y; acc[p][2] = b0.z; acc[p][3] = b0.w;
      acc[p][4] = b1.x; acc[p][5] = b1.y; acc[p][6] = b1.z; acc[p][7] = b1.w;
    }
  }

  for (int ky = 0; ky < 3; ky++) {
    for (int kx = 0; kx < 3; kx++) {
      const int tap = ky * 3 + kx;
      const float* wtap = w + (size_t)tap * 129 * 128;
      {   // time channel: only where tap input pos is inside the image (SAME zero-pad)
        float4 wa = *(const float4*)&wtap[co0];
        float4 wb = *(const float4*)&wtap[co0 + 4];
        int gy = ty0 + py + ky - 1;
        bool yok = (gy >= 0 && gy < 64);
        #pragma unroll
        for (int p = 0; p < 4; p++) {
          int gx = tx0 + px0 + p + kx - 1;
          float m = (yok && gx >= 0 && gx < 64) ? ts : 0.0f;
          acc[p][0] += m * wa.x; acc[p][1] += m * wa.y; acc[p][2] += m * wa.z; acc[p][3] += m * wa.w;
          acc[p][4] += m * wb.x; acc[p][5] += m * wb.y; acc[p][6] += m * wb.z; acc[p][7] += m * wb.w;
        }
      }
      const int ibase = ((py + ky) * 10 + (px0 + kx)) * 132;
      for (int c0 = 0; c0 < 128; c0 += 16) {
        __syncthreads();
        #pragma unroll
        for (int l = 0; l < 2; l++) {
          int idx = tid + l * 256;
          int ci = idx >> 5, c4 = (idx & 31) << 2;
          *(float4*)&w_lds[ci * 128 + c4] = *(const float4*)&wtap[(size_t)(1 + c0 + ci) * 128 + c4];
        }
        __syncthreads();
        #pragma unroll
        for (int q = 0; q < 4; q++) {
          float4 av[4];
          #pragma unroll
          for (int p = 0; p < 4; p++)
            av[p] = *(const float4*)&in_lds[ibase + p * 132 + c0 + q * 4];
          #pragma unroll
          for (int j = 0; j < 4; j++) {
            float4 w0 = *(const float4*)&w_lds[(q * 4 + j) * 128 + co0];
            float4 w1 = *(const float4*)&w_lds[(q * 4 + j) * 128 + co0 + 4];
            #pragma unroll
            for (int p = 0; p < 4; p++) {
              float a = ((const float*)&av[p])[j];
              acc[p][0] += a * w0.x; acc[p][1] += a * w0.y; acc[p][2] += a * w0.z; acc[p][3] += a * w0.w;
              acc[p][4] += a * w1.x; acc[p][5] += a * w1.y; acc[p][6] += a * w1.z; acc[p][7] += a * w1.w;
            }
          }
        }
      }
    }
  }
  #pragma unroll
  for (int p = 0; p < 4; p++) {
    size_t ob = (((size_t)(b * 64 + ty0 + py)) * 64 + (tx0 + px0 + p)) * 128 + co0;
    float4 v0 = make_float4(fmaxf(acc[p][0], 0.f), fmaxf(acc[p][1], 0.f), fmaxf(acc[p][2], 0.f), fmaxf(acc[p][3], 0.f));
    float4 v1 = make_float4(fmaxf(acc[p][4], 0.f), fmaxf(acc[p][5], 0.f), fmaxf(acc[p][6], 0.f), fmaxf(acc[p][7], 0.f));
    *(float4*)&out[ob] = v0;
    *(float4*)&out[ob + 4] = v1;
  }
}

// ---- error norm: errsum += sum((err/scale)^2), double accumulation ----------
__global__ __launch_bounds__(256) void err_kernel(Scal* __restrict__ scal,
    const float* __restrict__ y, const float* __restrict__ y5,
    const float* __restrict__ k1, const float* __restrict__ k3,
    const float* __restrict__ k4, const float* __restrict__ k5,
    const float* __restrict__ k6, const float* __restrict__ k7) {
  if (scal->done) return;
  const float hs = scal->hs;
  const float E1 = (float)(71.0/57600.0),  E3 = (float)(-71.0/16695.0);
  const float E4 = (float)(71.0/1920.0),   E5 = (float)(-17253.0/339200.0);
  const float E6 = (float)(22.0/525.0),    E7 = (float)(-1.0/40.0);
  int gid = blockIdx.x * 256 + threadIdx.x;   // 65536 threads
  double local = 0.0;
  for (int it = 0; it < 8; it++) {
    int i = gid + it * 65536;
    float4 vy = ((const float4*)y)[i];
    float4 v5 = ((const float4*)y5)[i];
    float4 a = ((const float4*)k1)[i];
    float4 b = ((const float4*)k3)[i];
    float4 c = ((const float4*)k4)[i];
    float4 d = ((const float4*)k5)[i];
    float4 e = ((const float4*)k6)[i];
    float4 f = ((const float4*)k7)[i];
    #pragma unroll
    for (int j = 0; j < 4; j++) {
      float s1 = ((const float*)&a)[j], s3 = ((const float*)&b)[j];
      float s4 = ((const float*)&c)[j], s5 = ((const float*)&d)[j];
      float s6 = ((const float*)&e)[j], s7 = ((const float*)&f)[j];
      float er = hs * (E1*s1 + E3*s3 + E4*s4 + E5*s5 + E6*s6 + E7*s7);
      float yv = ((const float*)&vy)[j], y5v = ((const float*)&v5)[j];
      float sc = 1e-3f + 1e-3f * fmaxf(fabsf(yv), fabsf(y5v));
      float r = er / sc;
      local += (double)(r * r);
    }
  }
  for (int off = 32; off > 0; off >>= 1) local += __shfl_down(local, off);
  __shared__ double wsum[4];
  int lane = threadIdx.x & 63, wv = threadIdx.x >> 6;
  if (lane == 0) wsum[wv] = local;
  __syncthreads();
  if (threadIdx.x == 0) {
    double s = wsum[0] + wsum[1] + wsum[2] + wsum[3];
    atomicAdd(&scal->errsum, s);
  }
}

__global__ __launch_bounds__(256) void upd_kernel(const Scal* __restrict__ scal,
    float* __restrict__ y, const float* __restrict__ y5) {
  if (!scal->accept) return;
  int i = blockIdx.x * 256 + threadIdx.x;
  ((float4*)y)[i] = ((const float4*)y5)[i];
}

// ---- output head: 1x1 conv 64 -> 10 (no time channel), dtype-branched store --
__global__ __launch_bounds__(256) void head_kernel(const Scal* __restrict__ scal,
    const float* __restrict__ y, const float* __restrict__ wo,
    const float* __restrict__ bo, void* __restrict__ out) {
  __shared__ float w_lds[640];
  __shared__ float b_lds[10];
  int tid = threadIdx.x;
  for (int i = tid; i < 640; i += 256) w_lds[i] = wo[i];
  if (tid < 10) b_lds[tid] = bo[tid];
  __syncthreads();
  int pix = blockIdx.x * 256 + tid;
  const float4* yv = (const float4*)(y + (size_t)pix * 64);
  float acc[10];
  #pragma unroll
  for (int o = 0; o < 10; o++) acc[o] = b_lds[o];
  for (int k4 = 0; k4 < 16; k4++) {
    float4 v = yv[k4];
    #pragma unroll
    for (int j = 0; j < 4; j++) {
      float a = ((const float*)&v)[j];
      int k = k4 * 4 + j;
      #pragma unroll
      for (int o = 0; o < 10; o++) acc[o] += a * w_lds[k * 10 + o];
    }
  }
  if (scal->is_bf16) {
    unsigned short* o16 = (unsigned short*)out;
    #pragma unroll
    for (int o = 0; o < 10; o++) o16[(size_t)pix * 10 + o] = f2bf(acc[o]);
  } else {
    float* of = (float*)out;
    #pragma unroll
    for (int o = 0; o < 10; o++) of[(size_t)pix * 10 + o] = acc[o];
  }
}

extern "C" void kernel_launch(void* const* d_in, const int* in_sizes, int n_in,
                              void* d_out, int out_size, void* d_ws, size_t ws_size,
                              hipStream_t stream) {
  (void)in_sizes; (void)n_in; (void)out_size; (void)ws_size;
  char* wsb = (char*)d_ws;
  Scal* scal = (Scal*)wsb;
  float* base = (float*)(wsb + 256);
  float* y = base;
  float* K[7];
  for (int s = 0; s < 7; s++) K[s] = base + (size_t)NYF * (1 + s);
  float* ytmp = base + (size_t)NYF * 8;
  float* y5   = base + (size_t)NYF * 9;
  float* h1b  = base + (size_t)NYF * 10;   // [NPIX][128]
  float* h2b  = base + (size_t)NYF * 12;   // [NPIX][128]
  float* wbuf = base + (size_t)NYF * 14;
  float* w1f = wbuf;           float* b1f = wbuf + 8320;
  float* w2f = wbuf + 8448;    float* b2f = wbuf + 157056;
  float* w3f = wbuf + 157184;  float* b3f = wbuf + 165440;
  float* wof = wbuf + 165504;  float* bof = wbuf + 166144;

  // dopri5 tableau (f32 exactly as JAX weak-typed scalars)
  const float cA21 = (float)(1.0/5.0);
  const float cA31 = (float)(3.0/40.0),       cA32 = (float)(9.0/40.0);
  const float cA41 = (float)(44.0/45.0),      cA42 = (float)(-56.0/15.0),    cA43 = (float)(32.0/9.0);
  const float cA51 = (float)(19372.0/6561.0), cA52 = (float)(-25360.0/2187.0);
  const float cA53 = (float)(64448.0/6561.0), cA54 = (float)(-212.0/729.0);
  const float cA61 = (float)(9017.0/3168.0),  cA62 = (float)(-355.0/33.0);
  const float cA63 = (float)(46732.0/5247.0), cA64 = (float)(49.0/176.0),    cA65 = (float)(-5103.0/18656.0);
  const float cB1 = (float)(35.0/384.0),  cB3 = (float)(500.0/1113.0), cB4 = (float)(125.0/192.0);
  const float cB5 = (float)(-2187.0/6784.0), cB6 = (float)(11.0/84.0);
  const float cC2 = 0.2f, cC3 = 0.3f, cC4 = 0.8f, cC5 = (float)(8.0/9.0);

  detect_kernel<<<1, 64, 0, stream>>>(scal, d_in[0]);
  convert_x_kernel<<<NYF / 1024, 256, 0, stream>>>(scal, d_in[0], y);
  convert_w_kernel<<<(166154 + 255) / 256, 256, 0, stream>>>(scal,
      d_in[1], d_in[2], d_in[3], d_in[4], d_in[5], d_in[6], d_in[7], d_in[8], wbuf);

  auto odef = [&](const float* yin, float cs, float* kout) {
    conv1x1_kernel<64, 128, 8, 256, true><<<NPIXT / 64, 256, 0, stream>>>(scal, cs, yin, w1f, b1f, h1b);
    conv3x3_kernel<<<512, 256, 0, stream>>>(scal, cs, h1b, w2f, b2f, h2b);
    conv1x1_kernel<128, 64, 4, 128, false><<<NPIXT / 32, 128, 0, stream>>>(scal, cs, h2b, w3f, b3f, kout);
  };

  for (int it = 0; it < 32; it++) {
    prep_kernel<<<1, 1, 0, stream>>>(scal);
    odef(y, 0.0f, K[0]);
    axpy_kernel<1><<<NYF/1024, 256, 0, stream>>>(scal, y, ytmp, K[0], K[0], K[0], K[0], K[0], cA21, 0, 0, 0, 0);
    odef(ytmp, cC2, K[1]);
    axpy_kernel<2><<<NYF/1024, 256, 0, stream>>>(scal, y, ytmp, K[0], K[1], K[1], K[1], K[1], cA31, cA32, 0, 0, 0);
    odef(ytmp, cC3, K[2]);
    axpy_kernel<3><<<NYF/1024, 256, 0, stream>>>(scal, y, ytmp, K[0], K[1], K[2], K[2], K[2], cA41, cA42, cA43, 0, 0);
    odef(ytmp, cC4, K[3]);
    axpy_kernel<4><<<NYF/1024, 256, 0, stream>>>(scal, y, ytmp, K[0], K[1], K[2], K[3], K[3], cA51, cA52, cA53, cA54, 0);
    odef(ytmp, cC5, K[4]);
    axpy_kernel<5><<<NYF/1024, 256, 0, stream>>>(scal, y, ytmp, K[0], K[1], K[2], K[3], K[4], cA61, cA62, cA63, cA64, cA65);
    odef(ytmp, 1.0f, K[5]);
    axpy_kernel<5><<<NYF/1024, 256, 0, stream>>>(scal, y, y5, K[0], K[2], K[3], K[4], K[5], cB1, cB3, cB4, cB5, cB6);
    odef(y5, 1.0f, K[6]);
    err_kernel<<<256, 256, 0, stream>>>(scal, y, y5, K[0], K[2], K[3], K[4], K[5], K[6]);
    accept_kernel<<<1, 1, 0, stream>>>(scal);
    upd_kernel<<<NYF/1024, 256, 0, stream>>>(scal, y, y5);
  }
  head_kernel<<<NPIXT / 256, 256, 0, stream>>>(scal, y, wof, bof, d_out);
}

// Round 3
// 3048.739 us; speedup vs baseline: 2.3522x; 2.3522x over previous
//
#include <hip/hip_runtime.h>

// Conv2dODENet dopri5: R1-proven fp32 pipeline, with ONLY the 3x3 conv on MFMA
// (RNE 2-way split bf16, 4-product => ~2^-18 rel error, fp32-equivalent here).
#define NYF   2097152   // 8*64*64*64
#define NPIXT 32768     // 8*64*64

struct Scal {
  double errsum;
  float t, h, hs;
  int done, accept, is_bf16;
};

using frag8 = __attribute__((ext_vector_type(8))) short;   // 8 bf16 (4 VGPRs)
using f32x4 = __attribute__((ext_vector_type(4))) float;   // 4 fp32 acc

static __device__ __forceinline__ float bf2f(unsigned short u) {
  return __uint_as_float(((unsigned)u) << 16);
}
static __device__ __forceinline__ unsigned short f2bf(float f) {
  unsigned u = __float_as_uint(f);
  u += 0x7FFFu + ((u >> 16) & 1u);   // RNE
  return (unsigned short)(u >> 16);
}
// RNE-balanced split: hi = RNE(f), lo = RNE(f - hi). |f-(hi+lo)| <= 2^-18|f|.
static __device__ __forceinline__ void split2(float f, unsigned short& h, unsigned short& l) {
  h = f2bf(f);
  float hf = bf2f(h);
  l = f2bf(f - hf);
}

// ---- dtype detection + scalar-state init (runs every call) -----------------
__global__ void detect_kernel(Scal* scal, const void* x) {
  if (threadIdx.x == 0 && blockIdx.x == 0) {
    const unsigned short* u = (const unsigned short*)x;
    int cnt = 0;
    for (int i = 0; i < 256; i++) {
      int e = (u[2 * i] >> 7) & 0xFF;
      if (e >= 100 && e <= 140) cnt++;
    }
    scal->is_bf16 = (cnt >= 200);
    scal->t = 0.0f; scal->h = 0.1f; scal->hs = 0.1f;
    scal->done = 0; scal->accept = 0; scal->errsum = 0.0;
  }
}

__global__ __launch_bounds__(256) void convert_x_kernel(const Scal* __restrict__ scal,
    const void* __restrict__ x, float* __restrict__ y) {
  int i = blockIdx.x * 256 + threadIdx.x;
  float4 v;
  if (scal->is_bf16) {
    ushort4 u = ((const ushort4*)x)[i];
    v.x = bf2f(u.x); v.y = bf2f(u.y); v.z = bf2f(u.z); v.w = bf2f(u.w);
  } else {
    v = ((const float4*)x)[i];
  }
  ((float4*)y)[i] = v;
}

__global__ __launch_bounds__(256) void convert_w_kernel(const Scal* __restrict__ scal,
    const void* s0, const void* s1, const void* s2, const void* s3,
    const void* s4, const void* s5, const void* s6, const void* s7,
    float* __restrict__ wbuf) {
  const void* srcs[8] = {s0, s1, s2, s3, s4, s5, s6, s7};
  const int cum[9] = {0, 8320, 8448, 157056, 157184, 165440, 165504, 166144, 166154};
  int idx = blockIdx.x * 256 + threadIdx.x;
  if (idx >= 166154) return;
  int seg = 0;
  while (idx >= cum[seg + 1]) seg++;
  int local = idx - cum[seg];
  float v = scal->is_bf16 ? bf2f(((const unsigned short*)srcs[seg])[local])
                          : ((const float*)srcs[seg])[local];
  wbuf[idx] = v;
}

// ---- pack conv2 weights -> MFMA B-frags, RNE hi/lo -------------------------
// Per (tap, kc): [nt(8)][2(hi,lo)][lane(64)*8]; B element (k,n): lane=quad*16+(n&15),
// j=k&7, quad=(k&31)>>3, kc=cin>>5, nt=n>>4. Total 9*4*8192 ushorts.
__global__ __launch_bounds__(256) void pack_w2_kernel(const float* __restrict__ wbuf,
    unsigned short* __restrict__ Wm2) {
  int idx = blockIdx.x * 256 + threadIdx.x;
  if (idx >= 147456) return;
  int k = idx >> 7, n = idx & 127;
  int tap = k >> 7, cin = k & 127;
  float f = wbuf[8448 + tap * 16512 + (1 + cin) * 128 + n];
  int kc = cin >> 5, kin = cin & 31, quad = kin >> 3, j = kin & 7;
  int nt = n >> 4, lane = quad * 16 + (n & 15);
  unsigned short* dhi = Wm2 + (size_t)(tap * 4 + kc) * 8192 + (nt * 2) * 512 + lane * 8 + j;
  unsigned short h, l; split2(f, h, l);
  dhi[0] = h; dhi[512] = l;
}

// ---- dopri5 scalar control (R1-verbatim) ------------------------------------
__global__ void prep_kernel(Scal* scal) {
  float t = scal->t, h = scal->h;
  int done = (t >= 1.0f) ? 1 : 0;
  float hs = fminf(h, 1.0f - t);
  scal->hs = hs; scal->done = done;
  scal->accept = 0; scal->errsum = 0.0;
}

__global__ void accept_kernel(Scal* scal) {
  int done = scal->done;
  float hs = scal->hs;
  float en = sqrtf((float)(scal->errsum / (double)NYF));
  int accept = (en <= 1.0f && !done) ? 1 : 0;
  scal->accept = accept;
  if (accept) scal->t = scal->t + hs;
  if (!done) {
    float en_s = fmaxf(en, 1e-8f);
    float fac = 0.9f * powf(en_s, -0.2f);
    fac = fminf(fmaxf(fac, 0.2f), 10.0f);
    scal->h = fmaxf(hs * fac, 1e-4f);
  }
}

// ---- conv1 (1x1, 64->128, relu) fp32, R1 body + fused stage-axpy staging ----
template<int NK>
__global__ __launch_bounds__(256) void conv1f_kernel(const Scal* __restrict__ scal, float cs,
    const float* __restrict__ y,
    const float* __restrict__ k0, const float* __restrict__ k1,
    const float* __restrict__ k2, const float* __restrict__ k3,
    const float* __restrict__ k4,
    float c0, float c1, float c2, float c3, float c4,
    const float* __restrict__ w, const float* __restrict__ bias,
    float* __restrict__ out) {
  if (scal->done) return;
  // KIN=64 NOUT=128 CPT=8 NT=256 -> NCG=16 NPG=16 PIX=64 RS=68 (R1-proven)
  __shared__ float in_lds[64 * 68];
  __shared__ float w_lds[65 * 128];
  const int tid = threadIdx.x;
  const int cg = tid % 16;
  const int pg = tid / 16;
  const int pix0 = blockIdx.x * 64;
  const float hs = scal->hs;
  const float ts = scal->t + cs * hs;

  for (int idx = tid; idx < 2080; idx += 256)
    ((float4*)w_lds)[idx] = ((const float4*)w)[idx];

  const float4* yb = (const float4*)(y + (size_t)pix0 * 64);
  const float4* p0 = (const float4*)(k0 + (size_t)pix0 * 64);
  const float4* p1 = (const float4*)(k1 + (size_t)pix0 * 64);
  const float4* p2 = (const float4*)(k2 + (size_t)pix0 * 64);
  const float4* p3 = (const float4*)(k3 + (size_t)pix0 * 64);
  const float4* p4 = (const float4*)(k4 + (size_t)pix0 * 64);
  for (int idx = tid; idx < 1024; idx += 256) {
    float4 v = yb[idx];
    if constexpr (NK > 0) {
      float4 q = p0[idx];
      float sx = c0 * q.x, sy = c0 * q.y, sz = c0 * q.z, sw = c0 * q.w;
      if constexpr (NK > 1) { q = p1[idx]; sx += c1*q.x; sy += c1*q.y; sz += c1*q.z; sw += c1*q.w; }
      if constexpr (NK > 2) { q = p2[idx]; sx += c2*q.x; sy += c2*q.y; sz += c2*q.z; sw += c2*q.w; }
      if constexpr (NK > 3) { q = p3[idx]; sx += c3*q.x; sy += c3*q.y; sz += c3*q.z; sw += c3*q.w; }
      if constexpr (NK > 4) { q = p4[idx]; sx += c4*q.x; sy += c4*q.y; sz += c4*q.z; sw += c4*q.w; }
      v.x += hs * sx; v.y += hs * sy; v.z += hs * sz; v.w += hs * sw;
    }
    int p = idx >> 4, c4i = (idx & 15) << 2;
    *(float4*)&in_lds[p * 68 + c4i] = v;
  }
  __syncthreads();

  const int co0 = cg * 8;
  float acc[4][8];
  #pragma unroll
  for (int j4 = 0; j4 < 2; j4++) {
    float4 bv = *(const float4*)&bias[co0 + j4 * 4];
    float4 wt = *(const float4*)&w_lds[co0 + j4 * 4];   // time row
    float i0 = bv.x + ts * wt.x, i1 = bv.y + ts * wt.y;
    float i2 = bv.z + ts * wt.z, i3 = bv.w + ts * wt.w;
    #pragma unroll
    for (int p = 0; p < 4; p++) {
      acc[p][j4*4+0] = i0; acc[p][j4*4+1] = i1;
      acc[p][j4*4+2] = i2; acc[p][j4*4+3] = i3;
    }
  }
  const int ib = (pg * 4) * 68;
  #pragma unroll 4
  for (int k4 = 0; k4 < 16; k4++) {
    float4 av[4];
    #pragma unroll
    for (int p = 0; p < 4; p++)
      av[p] = *(const float4*)&in_lds[ib + p * 68 + k4 * 4];
    #pragma unroll
    for (int j = 0; j < 4; j++) {
      #pragma unroll
      for (int j4 = 0; j4 < 2; j4++) {
        float4 wv = *(const float4*)&w_lds[(1 + k4 * 4 + j) * 128 + co0 + j4 * 4];
        #pragma unroll
        for (int p = 0; p < 4; p++) {
          float a = ((const float*)&av[p])[j];
          acc[p][j4*4+0] += a * wv.x; acc[p][j4*4+1] += a * wv.y;
          acc[p][j4*4+2] += a * wv.z; acc[p][j4*4+3] += a * wv.w;
        }
      }
    }
  }
  #pragma unroll
  for (int p = 0; p < 4; p++) {
    size_t ob = (size_t)(pix0 + pg * 4 + p) * 128 + co0;
    #pragma unroll
    for (int j4 = 0; j4 < 2; j4++) {
      float4 v;
      v.x = fmaxf(acc[p][j4*4+0], 0.f); v.y = fmaxf(acc[p][j4*4+1], 0.f);
      v.z = fmaxf(acc[p][j4*4+2], 0.f); v.w = fmaxf(acc[p][j4*4+3], 0.f);
      *(float4*)&out[ob + j4 * 4] = v;
    }
  }
}

// ---- generic fp32 1x1 (R1-verbatim) for conv3's 129->64 --------------------
template<int KIN, int NOUT, int CPT, int NT, bool RELU>
__global__ __launch_bounds__(NT) void conv1x1_kernel(const Scal* __restrict__ scal, float cs,
    const float* __restrict__ in, const float* __restrict__ w,
    const float* __restrict__ bias, float* __restrict__ out) {
  if (scal->done) return;
  constexpr int NCG = NOUT / CPT;
  constexpr int NPG = NT / NCG;
  constexpr int PIX = NPG * 4;
  constexpr int RS = KIN + 4;
  __shared__ float in_lds[PIX * RS];
  __shared__ float w_lds[(KIN + 1) * NOUT];
  const int tid = threadIdx.x;
  const int cg = tid % NCG;
  const int pg = tid / NCG;
  const int pix0 = blockIdx.x * PIX;
  const float ts = scal->t + cs * scal->hs;

  for (int idx = tid; idx < (KIN + 1) * NOUT / 4; idx += NT)
    ((float4*)w_lds)[idx] = ((const float4*)w)[idx];
  const float4* inb = (const float4*)(in + (size_t)pix0 * KIN);
  for (int idx = tid; idx < PIX * KIN / 4; idx += NT) {
    int p = idx / (KIN / 4);
    int c4 = (idx % (KIN / 4)) * 4;
    *(float4*)&in_lds[p * RS + c4] = inb[idx];
  }
  __syncthreads();

  const int co0 = cg * CPT;
  float acc[4][CPT];
  #pragma unroll
  for (int j4 = 0; j4 < CPT / 4; j4++) {
    float4 bv = *(const float4*)&bias[co0 + j4 * 4];
    float4 wt = *(const float4*)&w_lds[co0 + j4 * 4];
    float i0 = bv.x + ts * wt.x, i1 = bv.y + ts * wt.y;
    float i2 = bv.z + ts * wt.z, i3 = bv.w + ts * wt.w;
    #pragma unroll
    for (int p = 0; p < 4; p++) {
      acc[p][j4*4+0] = i0; acc[p][j4*4+1] = i1;
      acc[p][j4*4+2] = i2; acc[p][j4*4+3] = i3;
    }
  }
  const int ib = (pg * 4) * RS;
  #pragma unroll 4
  for (int k4 = 0; k4 < KIN / 4; k4++) {
    float4 av[4];
    #pragma unroll
    for (int p = 0; p < 4; p++)
      av[p] = *(const float4*)&in_lds[ib + p * RS + k4 * 4];
    #pragma unroll
    for (int j = 0; j < 4; j++) {
      #pragma unroll
      for (int j4 = 0; j4 < CPT / 4; j4++) {
        float4 wv = *(const float4*)&w_lds[(1 + k4 * 4 + j) * NOUT + co0 + j4 * 4];
        #pragma unroll
        for (int p = 0; p < 4; p++) {
          float a = ((const float*)&av[p])[j];
          acc[p][j4*4+0] += a * wv.x; acc[p][j4*4+1] += a * wv.y;
          acc[p][j4*4+2] += a * wv.z; acc[p][j4*4+3] += a * wv.w;
        }
      }
    }
  }
  #pragma unroll
  for (int p = 0; p < 4; p++) {
    size_t ob = (size_t)(pix0 + pg * 4 + p) * NOUT + co0;
    #pragma unroll
    for (int j4 = 0; j4 < CPT / 4; j4++) {
      float4 v;
      v.x = acc[p][j4*4+0]; v.y = acc[p][j4*4+1];
      v.z = acc[p][j4*4+2]; v.w = acc[p][j4*4+3];
      if (RELU) { v.x = fmaxf(v.x, 0.f); v.y = fmaxf(v.y, 0.f); v.z = fmaxf(v.z, 0.f); v.w = fmaxf(v.w, 0.f); }
      *(float4*)&out[ob + j4 * 4] = v;
    }
  }
}

// ---- conv3x3 SAME 129->128 relu: MFMA, fp32 global I/O ----------------------
// 256 thr / 4 waves; 8x8 spatial x 128 couts per block. Wave: 32 px x 64 couts.
// Input staged per 64-cin half, split RNE hi/lo in LDS. 4-product MFMA.
__global__ __launch_bounds__(256) void conv3m_kernel(const Scal* __restrict__ scal, float cs,
    const float* __restrict__ gin, const float* __restrict__ wbuf,
    const unsigned short* __restrict__ Wm2, float* __restrict__ out) {
  if (scal->done) return;
  __shared__ __align__(16) unsigned short t_hi[100 * 72];  // 10x10 halo x 64 cin
  __shared__ __align__(16) unsigned short t_lo[100 * 72];
  __shared__ __align__(16) unsigned short wch[8192];       // one (tap,kc) chunk
  const int tid = threadIdx.x;
  const int b = blockIdx.x >> 6, tile = blockIdx.x & 63;
  const int ty0 = (tile >> 3) << 3, tx0 = (tile & 7) << 3;
  const float ts = scal->t + cs * scal->hs;
  const int w = tid >> 6, lane = tid & 63, quad = lane >> 4, nl = lane & 15;
  const int pxw = (w & 1) * 32;          // pixel half within the 64-px tile
  const int ntb = (w >> 1) * 4;          // n-tile base (4 tiles of 16 couts)
  const int m0 = pxw + nl, m1 = m0 + 16;
  const int pos0 = (m0 >> 3) * 10 + (m0 & 7);
  const int pos1 = (m1 >> 3) * 10 + (m1 & 7);

  const f32x4 z4 = {0.f, 0.f, 0.f, 0.f};
  f32x4 acc[2][4];
  for (int mt = 0; mt < 2; mt++) for (int nt = 0; nt < 4; nt++) acc[mt][nt] = z4;

  for (int ch = 0; ch < 2; ch++) {
    __syncthreads();   // previous half's t_* reads complete
    for (int idx = tid; idx < 1600; idx += 256) {    // 100 pos x 16 float4
      int pos = idx >> 4, c4 = (idx & 15) << 2;
      int iy = pos / 10, ix = pos - iy * 10;
      int gy = ty0 + iy - 1, gx = tx0 + ix - 1;
      float4 v = make_float4(0.f, 0.f, 0.f, 0.f);
      if (gy >= 0 && gy < 64 && gx >= 0 && gx < 64)
        v = *(const float4*)&gin[(size_t)(((b * 64 + gy) * 64) + gx) * 128 + ch * 64 + c4];
      unsigned short ha, hb, hc, hd, la, lb, lc, ld;
      split2(v.x, ha, la); split2(v.y, hb, lb); split2(v.z, hc, lc); split2(v.w, hd, ld);
      short4 hv; hv.x = (short)ha; hv.y = (short)hb; hv.z = (short)hc; hv.w = (short)hd;
      short4 lv; lv.x = (short)la; lv.y = (short)lb; lv.z = (short)lc; lv.w = (short)ld;
      *(short4*)&t_hi[pos * 72 + c4] = hv;
      *(short4*)&t_lo[pos * 72 + c4] = lv;
    }
    for (int ky = 0; ky < 3; ky++) {
      for (int kx = 0; kx < 3; kx++) {
        const int tap = ky * 3 + kx;
        const int a0 = (pos0 + ky * 10 + kx) * 72 + quad * 8;
        const int a1 = (pos1 + ky * 10 + kx) * 72 + quad * 8;
        for (int kc2 = 0; kc2 < 2; kc2++) {
          __syncthreads();   // previous wch reads complete (also orders t_* staging)
          const int4* wsrc = (const int4*)(Wm2 + (size_t)(tap * 4 + ch * 2 + kc2) * 8192);
          ((int4*)wch)[tid]       = wsrc[tid];
          ((int4*)wch)[tid + 256] = wsrc[tid + 256];
          ((int4*)wch)[tid + 512] = wsrc[tid + 512];
          ((int4*)wch)[tid + 768] = wsrc[tid + 768];
          __syncthreads();
          frag8 Ah0 = *(const frag8*)&t_hi[a0 + kc2 * 32];
          frag8 Al0 = *(const frag8*)&t_lo[a0 + kc2 * 32];
          frag8 Ah1 = *(const frag8*)&t_hi[a1 + kc2 * 32];
          frag8 Al1 = *(const frag8*)&t_lo[a1 + kc2 * 32];
          #pragma unroll
          for (int nt = 0; nt < 4; nt++) {
            frag8 Bh = *(const frag8*)&wch[((ntb + nt) * 2    ) * 512 + lane * 8];
            frag8 Bl = *(const frag8*)&wch[((ntb + nt) * 2 + 1) * 512 + lane * 8];
            acc[0][nt] = __builtin_amdgcn_mfma_f32_16x16x32_bf16(Ah0, Bh, acc[0][nt], 0, 0, 0);
            acc[0][nt] = __builtin_amdgcn_mfma_f32_16x16x32_bf16(Al0, Bh, acc[0][nt], 0, 0, 0);
            acc[0][nt] = __builtin_amdgcn_mfma_f32_16x16x32_bf16(Ah0, Bl, acc[0][nt], 0, 0, 0);
            acc[0][nt] = __builtin_amdgcn_mfma_f32_16x16x32_bf16(Al0, Bl, acc[0][nt], 0, 0, 0);
            acc[1][nt] = __builtin_amdgcn_mfma_f32_16x16x32_bf16(Ah1, Bh, acc[1][nt], 0, 0, 0);
            acc[1][nt] = __builtin_amdgcn_mfma_f32_16x16x32_bf16(Al1, Bh, acc[1][nt], 0, 0, 0);
            acc[1][nt] = __builtin_amdgcn_mfma_f32_16x16x32_bf16(Ah1, Bl, acc[1][nt], 0, 0, 0);
            acc[1][nt] = __builtin_amdgcn_mfma_f32_16x16x32_bf16(Al1, Bl, acc[1][nt], 0, 0, 0);
          }
        }
      }
    }
  }

  // epilogue: bias + time channel (SAME zero-pad border masks) + relu, fp32 out
  const float* b2p = wbuf + 157056;
  const float* w2t = wbuf + 8448;   // [tap][129][128], cin row 0 = time
  for (int nt = 0; nt < 4; nt++) {
    int cout = (ntb + nt) * 16 + nl;
    float bb = b2p[cout];
    float wt[9];
    #pragma unroll
    for (int tap = 0; tap < 9; tap++) wt[tap] = w2t[tap * 16512 + cout];
    #pragma unroll
    for (int mt = 0; mt < 2; mt++) {
      #pragma unroll
      for (int r = 0; r < 4; r++) {
        int m = pxw + mt * 16 + quad * 4 + r;
        int oy = ty0 + (m >> 3), ox = tx0 + (m & 7);
        float tadd = 0.f;
        #pragma unroll
        for (int ky = 0; ky < 3; ky++) {
          int iy = oy + ky - 1;
          bool yok = (iy >= 0 && iy < 64);
          #pragma unroll
          for (int kx = 0; kx < 3; kx++) {
            int ix = ox + kx - 1;
            if (yok && ix >= 0 && ix < 64) tadd += wt[ky * 3 + kx];
          }
        }
        float v = fmaxf(acc[mt][nt][r] + bb + ts * tadd, 0.f);
        out[(size_t)(((b * 64 + oy) * 64) + ox) * 128 + cout] = v;
      }
    }
  }
}

// ---- stage-combination axpy (R1-verbatim), used for y5 ----------------------
template<int NK>
__global__ __launch_bounds__(256) void axpy_kernel(const Scal* __restrict__ scal,
    const float* __restrict__ y, float* __restrict__ out,
    const float* __restrict__ k0, const float* __restrict__ k1,
    const float* __restrict__ k2, const float* __restrict__ k3,
    const float* __restrict__ k4,
    float c0, float c1, float c2, float c3, float c4) {
  if (scal->done) return;
  const float hs = scal->hs;
  int i = blockIdx.x * 256 + threadIdx.x;
  float4 yv = ((const float4*)y)[i];
  float4 v = ((const float4*)k0)[i];
  float sx = c0 * v.x, sy = c0 * v.y, sz = c0 * v.z, sw = c0 * v.w;
  if constexpr (NK > 1) { float4 q = ((const float4*)k1)[i]; sx += c1*q.x; sy += c1*q.y; sz += c1*q.z; sw += c1*q.w; }
  if constexpr (NK > 2) { float4 q = ((const float4*)k2)[i]; sx += c2*q.x; sy += c2*q.y; sz += c2*q.z; sw += c2*q.w; }
  if constexpr (NK > 3) { float4 q = ((const float4*)k3)[i]; sx += c3*q.x; sy += c3*q.y; sz += c3*q.z; sw += c3*q.w; }
  if constexpr (NK > 4) { float4 q = ((const float4*)k4)[i]; sx += c4*q.x; sy += c4*q.y; sz += c4*q.z; sw += c4*q.w; }
  float4 o;
  o.x = yv.x + hs * sx; o.y = yv.y + hs * sy; o.z = yv.z + hs * sz; o.w = yv.w + hs * sw;
  ((float4*)out)[i] = o;
}

// ---- error norm (R1-verbatim) ----------------------------------------------
__global__ __launch_bounds__(256) void err_kernel(Scal* __restrict__ scal,
    const float* __restrict__ y, const float* __restrict__ y5,
    const float* __restrict__ k1, const float* __restrict__ k3,
    const float* __restrict__ k4, const float* __restrict__ k5,
    const float* __restrict__ k6, const float* __restrict__ k7) {
  if (scal->done) return;
  const float hs = scal->hs;
  const float E1 = (float)(71.0/57600.0),  E3 = (float)(-71.0/16695.0);
  const float E4 = (float)(71.0/1920.0),   E5 = (float)(-17253.0/339200.0);
  const float E6 = (float)(22.0/525.0),    E7 = (float)(-1.0/40.0);
  int gid = blockIdx.x * 256 + threadIdx.x;
  double local = 0.0;
  for (int it = 0; it < 8; it++) {
    int i = gid + it * 65536;
    float4 vy = ((const float4*)y)[i];
    float4 v5 = ((const float4*)y5)[i];
    float4 a = ((const float4*)k1)[i];
    float4 b = ((const float4*)k3)[i];
    float4 c = ((const float4*)k4)[i];
    float4 d = ((const float4*)k5)[i];
    float4 e = ((const float4*)k6)[i];
    float4 f = ((const float4*)k7)[i];
    #pragma unroll
    for (int j = 0; j < 4; j++) {
      float s1 = ((const float*)&a)[j], s3 = ((const float*)&b)[j];
      float s4 = ((const float*)&c)[j], s5 = ((const float*)&d)[j];
      float s6 = ((const float*)&e)[j], s7 = ((const float*)&f)[j];
      float er = hs * (E1*s1 + E3*s3 + E4*s4 + E5*s5 + E6*s6 + E7*s7);
      float yv = ((const float*)&vy)[j], y5v = ((const float*)&v5)[j];
      float sc = 1e-3f + 1e-3f * fmaxf(fabsf(yv), fabsf(y5v));
      float r = er / sc;
      local += (double)(r * r);
    }
  }
  for (int off = 32; off > 0; off >>= 1) local += __shfl_down(local, off);
  __shared__ double wsum[4];
  int lane = threadIdx.x & 63, wv = threadIdx.x >> 6;
  if (lane == 0) wsum[wv] = local;
  __syncthreads();
  if (threadIdx.x == 0) {
    double s = wsum[0] + wsum[1] + wsum[2] + wsum[3];
    atomicAdd(&scal->errsum, s);
  }
}

__global__ __launch_bounds__(256) void upd_kernel(const Scal* __restrict__ scal,
    float* __restrict__ y, const float* __restrict__ y5) {
  if (!scal->accept) return;
  int i = blockIdx.x * 256 + threadIdx.x;
  ((float4*)y)[i] = ((const float4*)y5)[i];
}

// ---- output head (R1-verbatim) ----------------------------------------------
__global__ __launch_bounds__(256) void head_kernel(const Scal* __restrict__ scal,
    const float* __restrict__ y, const float* __restrict__ wo,
    const float* __restrict__ bo, void* __restrict__ out) {
  __shared__ float w_lds[640];
  __shared__ float b_lds[10];
  int tid = threadIdx.x;
  for (int i = tid; i < 640; i += 256) w_lds[i] = wo[i];
  if (tid < 10) b_lds[tid] = bo[tid];
  __syncthreads();
  int pix = blockIdx.x * 256 + tid;
  const float4* yv = (const float4*)(y + (size_t)pix * 64);
  float acc[10];
  #pragma unroll
  for (int o = 0; o < 10; o++) acc[o] = b_lds[o];
  for (int k4 = 0; k4 < 16; k4++) {
    float4 v = yv[k4];
    #pragma unroll
    for (int j = 0; j < 4; j++) {
      float a = ((const float*)&v)[j];
      int k = k4 * 4 + j;
      #pragma unroll
      for (int o = 0; o < 10; o++) acc[o] += a * w_lds[k * 10 + o];
    }
  }
  if (scal->is_bf16) {
    unsigned short* o16 = (unsigned short*)out;
    #pragma unroll
    for (int o = 0; o < 10; o++) o16[(size_t)pix * 10 + o] = f2bf(acc[o]);
  } else {
    float* of = (float*)out;
    #pragma unroll
    for (int o = 0; o < 10; o++) of[(size_t)pix * 10 + o] = acc[o];
  }
}

extern "C" void kernel_launch(void* const* d_in, const int* in_sizes, int n_in,
                              void* d_out, int out_size, void* d_ws, size_t ws_size,
                              hipStream_t stream) {
  (void)in_sizes; (void)n_in; (void)out_size; (void)ws_size;
  char* wsb = (char*)d_ws;
  Scal* scal = (Scal*)wsb;
  float* base = (float*)(wsb + 256);
  float* y  = base;
  float* K[7];
  for (int s = 0; s < 7; s++) K[s] = base + (size_t)NYF * (1 + s);
  float* y5   = base + (size_t)NYF * 8;
  float* h1b  = base + (size_t)NYF * 9;    // [32768][128] fp32
  float* h2b  = base + (size_t)NYF * 11;   // [32768][128] fp32
  float* wbuf = base + (size_t)NYF * 13;   // 166154 floats (pad 166400)
  unsigned short* Wm2 = (unsigned short*)(wbuf + 166400);  // 294912 ushorts
  float* w1f = wbuf;           float* b1f = wbuf + 8320;
  float* w3f = wbuf + 157184;  float* b3f = wbuf + 165440;
  float* wof = wbuf + 165504;  float* bof = wbuf + 166144;

  const float cA21 = (float)(1.0/5.0);
  const float cA31 = (float)(3.0/40.0),       cA32 = (float)(9.0/40.0);
  const float cA41 = (float)(44.0/45.0),      cA42 = (float)(-56.0/15.0),    cA43 = (float)(32.0/9.0);
  const float cA51 = (float)(19372.0/6561.0), cA52 = (float)(-25360.0/2187.0);
  const float cA53 = (float)(64448.0/6561.0), cA54 = (float)(-212.0/729.0);
  const float cA61 = (float)(9017.0/3168.0),  cA62 = (float)(-355.0/33.0);
  const float cA63 = (float)(46732.0/5247.0), cA64 = (float)(49.0/176.0),    cA65 = (float)(-5103.0/18656.0);
  const float cB1 = (float)(35.0/384.0),  cB3 = (float)(500.0/1113.0), cB4 = (float)(125.0/192.0);
  const float cB5 = (float)(-2187.0/6784.0), cB6 = (float)(11.0/84.0);
  const float cC2 = 0.2f, cC3 = 0.3f, cC4 = 0.8f, cC5 = (float)(8.0/9.0);

  detect_kernel<<<1, 64, 0, stream>>>(scal, d_in[0]);
  convert_x_kernel<<<NYF / 1024, 256, 0, stream>>>(scal, d_in[0], y);
  convert_w_kernel<<<(166154 + 255) / 256, 256, 0, stream>>>(scal,
      d_in[1], d_in[2], d_in[3], d_in[4], d_in[5], d_in[6], d_in[7], d_in[8], wbuf);
  pack_w2_kernel<<<576, 256, 0, stream>>>(wbuf, Wm2);

  auto tail = [&](float cs, float* kout) {
    conv3m_kernel<<<512, 256, 0, stream>>>(scal, cs, h1b, wbuf, Wm2, h2b);
    conv1x1_kernel<128, 64, 4, 128, false><<<NPIXT / 32, 128, 0, stream>>>(scal, cs, h2b, w3f, b3f, kout);
  };

  for (int it = 0; it < 32; it++) {
    prep_kernel<<<1, 1, 0, stream>>>(scal);
    conv1f_kernel<0><<<512, 256, 0, stream>>>(scal, 0.0f, y, y, y, y, y, y, 0, 0, 0, 0, 0, w1f, b1f, h1b);
    tail(0.0f, K[0]);
    conv1f_kernel<1><<<512, 256, 0, stream>>>(scal, cC2, y, K[0], y, y, y, y, cA21, 0, 0, 0, 0, w1f, b1f, h1b);
    tail(cC2, K[1]);
    conv1f_kernel<2><<<512, 256, 0, stream>>>(scal, cC3, y, K[0], K[1], y, y, y, cA31, cA32, 0, 0, 0, w1f, b1f, h1b);
    tail(cC3, K[2]);
    conv1f_kernel<3><<<512, 256, 0, stream>>>(scal, cC4, y, K[0], K[1], K[2], y, y, cA41, cA42, cA43, 0, 0, w1f, b1f, h1b);
    tail(cC4, K[3]);
    conv1f_kernel<4><<<512, 256, 0, stream>>>(scal, cC5, y, K[0], K[1], K[2], K[3], y, cA51, cA52, cA53, cA54, 0, w1f, b1f, h1b);
    tail(cC5, K[4]);
    conv1f_kernel<5><<<512, 256, 0, stream>>>(scal, 1.0f, y, K[0], K[1], K[2], K[3], K[4], cA61, cA62, cA63, cA64, cA65, w1f, b1f, h1b);
    tail(1.0f, K[5]);
    axpy_kernel<5><<<NYF / 1024, 256, 0, stream>>>(scal, y, y5, K[0], K[2], K[3], K[4], K[5], cB1, cB3, cB4, cB5, cB6);
    conv1f_kernel<0><<<512, 256, 0, stream>>>(scal, 1.0f, y5, y5, y5, y5, y5, y5, 0, 0, 0, 0, 0, w1f, b1f, h1b);
    tail(1.0f, K[6]);
    err_kernel<<<256, 256, 0, stream>>>(scal, y, y5, K[0], K[2], K[3], K[4], K[5], K[6]);
    accept_kernel<<<1, 1, 0, stream>>>(scal);
    upd_kernel<<<NYF / 1024, 256, 0, stream>>>(scal, y, y5);
  }
  head_kernel<<<NPIXT / 256, 256, 0, stream>>>(scal, y, wof, bof, d_out);
}

// Round 4
// 1604.102 us; speedup vs baseline: 4.4706x; 1.9006x over previous
//
#include <hip/hip_runtime.h>

// Conv2dODENet dopri5: one fused kernel per RK stage (conv3+conv1b+axpy+conv1f),
// all GEMMs on split-bf16 MFMA (RNE hi/lo, 4 products == fp32-equivalent).
#define NYF   2097152   // 8*64*64*64
#define NPIXT 32768     // 8*64*64

struct Scal {
  double errsum;
  float t, h, hs;
  int done, accept, is_bf16;
};

using frag8 = __attribute__((ext_vector_type(8))) short;   // 8 bf16 (4 VGPRs)
using f32x4 = __attribute__((ext_vector_type(4))) float;   // 4 fp32 acc

static __device__ __forceinline__ float bf2f(unsigned short u) {
  return __uint_as_float(((unsigned)u) << 16);
}
static __device__ __forceinline__ unsigned short f2bf(float f) {
  unsigned u = __float_as_uint(f);
  u += 0x7FFFu + ((u >> 16) & 1u);   // RNE
  return (unsigned short)(u >> 16);
}
// RNE-balanced split: hi = RNE(f), lo = RNE(f - hi). |f-(hi+lo)| <= ~2^-18|f|.
static __device__ __forceinline__ void split2(float f, unsigned short& h, unsigned short& l) {
  h = f2bf(f);
  float hf = bf2f(h);
  l = f2bf(f - hf);
}

// ---- dtype detection + scalar-state init (runs every call) -----------------
__global__ void detect_kernel(Scal* scal, const void* x) {
  if (threadIdx.x == 0 && blockIdx.x == 0) {
    const unsigned short* u = (const unsigned short*)x;
    int cnt = 0;
    for (int i = 0; i < 256; i++) {
      int e = (u[2 * i] >> 7) & 0xFF;
      if (e >= 100 && e <= 140) cnt++;
    }
    scal->is_bf16 = (cnt >= 200);
    scal->t = 0.0f; scal->h = 0.1f; scal->hs = 0.1f;   // prep for iter 0
    scal->done = 0; scal->accept = 0; scal->errsum = 0.0;
  }
}

__global__ __launch_bounds__(256) void convert_x_kernel(const Scal* __restrict__ scal,
    const void* __restrict__ x, float* __restrict__ y) {
  int i = blockIdx.x * 256 + threadIdx.x;
  float4 v;
  if (scal->is_bf16) {
    ushort4 u = ((const ushort4*)x)[i];
    v.x = bf2f(u.x); v.y = bf2f(u.y); v.z = bf2f(u.z); v.w = bf2f(u.w);
  } else {
    v = ((const float4*)x)[i];
  }
  ((float4*)y)[i] = v;
}

__global__ __launch_bounds__(256) void convert_w_kernel(const Scal* __restrict__ scal,
    const void* s0, const void* s1, const void* s2, const void* s3,
    const void* s4, const void* s5, const void* s6, const void* s7,
    float* __restrict__ wbuf) {
  const void* srcs[8] = {s0, s1, s2, s3, s4, s5, s6, s7};
  const int cum[9] = {0, 8320, 8448, 157056, 157184, 165440, 165504, 166144, 166154};
  int idx = blockIdx.x * 256 + threadIdx.x;
  if (idx >= 166154) return;
  int seg = 0;
  while (idx >= cum[seg + 1]) seg++;
  int local = idx - cum[seg];
  float v = scal->is_bf16 ? bf2f(((const unsigned short*)srcs[seg])[local])
                          : ((const float*)srcs[seg])[local];
  wbuf[idx] = v;
}

// ---- pack all conv weights -> MFMA B-frags (proven R3 math), RNE hi/lo -----
// Per (kc): [nt][2(hi,lo)][512]; element (k,n): lane=quad*16+(n&15), j=k&7.
__global__ __launch_bounds__(256) void pack_all_kernel(const float* __restrict__ wbuf,
    unsigned short* __restrict__ Wm1, unsigned short* __restrict__ Wm2,
    unsigned short* __restrict__ Wm3) {
  int idx = blockIdx.x * 256 + threadIdx.x;
  if (idx >= 163840) return;
  float f; unsigned short* dhi;
  if (idx < 147456) {                 // w2: K=9*128, N=128 -> [tap*4+kc][nt(8)][2][512]
    int k = idx >> 7, n = idx & 127;
    int tap = k >> 7, cin = k & 127;
    f = wbuf[8448 + tap * 16512 + (1 + cin) * 128 + n];
    int kc = cin >> 5, kin = cin & 31, quad = kin >> 3, j = kin & 7;
    int nt = n >> 4, lane = quad * 16 + (n & 15);
    dhi = Wm2 + (size_t)(tap * 4 + kc) * 8192 + (nt * 2) * 512 + lane * 8 + j;
  } else if (idx < 155648) {          // w1: K=64, N=128 -> [kc(2)][nt(8)][2][512]
    int t2 = idx - 147456;
    int k = t2 >> 7, n = t2 & 127;
    f = wbuf[(1 + k) * 128 + n];
    int kc = k >> 5, kin = k & 31, quad = kin >> 3, j = kin & 7;
    int nt = n >> 4, lane = quad * 16 + (n & 15);
    dhi = Wm1 + ((kc * 8 + nt) * 2) * 512 + lane * 8 + j;
  } else {                            // w3: K=128, N=64 -> [kc(4)][nt(4)][2][512]
    int t2 = idx - 155648;
    int k = t2 >> 6, n = t2 & 63;
    f = wbuf[157184 + (1 + k) * 64 + n];
    int kc = k >> 5, kin = k & 31, quad = kin >> 3, j = kin & 7;
    int nt = n >> 4, lane = quad * 16 + (n & 15);
    dhi = Wm3 + ((kc * 4 + nt) * 2) * 512 + lane * 8 + j;
  }
  unsigned short h, l; split2(f, h, l);
  dhi[0] = h; dhi[512] = l;
}

// ---- dopri5 scalar control: accept + prep-next fused ------------------------
__global__ void accept_kernel(Scal* scal) {
  int done = scal->done;
  float hs = scal->hs;
  float en = sqrtf((float)(scal->errsum / (double)NYF));
  int accept = (en <= 1.0f && !done) ? 1 : 0;
  scal->accept = accept;
  float t = scal->t, h = scal->h;
  if (accept) t += hs;
  if (!done) {
    float en_s = fmaxf(en, 1e-8f);
    float fac = fminf(fmaxf(0.9f * powf(en_s, -0.2f), 0.2f), 10.0f);
    h = fmaxf(hs * fac, 1e-4f);
  }
  scal->t = t; scal->h = h;
  scal->done = (t >= 1.0f) ? 1 : 0;
  scal->hs = fminf(h, 1.0f - t);
  scal->errsum = 0.0;
}

// ---- iteration-start kernel: y <- y5 if accept; conv1f(y) -> h1 -------------
__global__ __launch_bounds__(256) void kfirst_kernel(const Scal* __restrict__ scal,
    const float* __restrict__ y5, float* __restrict__ y,
    const float* __restrict__ wbuf, const unsigned short* __restrict__ Wm1,
    float* __restrict__ h1out) {
  const int done = scal->done, acc = scal->accept;
  if (done && !acc) return;
  __shared__ __align__(16) char uni[34816];
  unsigned short* u_hi = (unsigned short*)uni;          // 64*72
  unsigned short* u_lo = u_hi + 4608;
  unsigned short* w1ch = (unsigned short*)(uni + 18432); // 8192 us per kc chunk
  const int tid = threadIdx.x;
  const int b = blockIdx.x >> 6, tile = blockIdx.x & 63;
  const int ty0 = (tile >> 3) << 3, tx0 = (tile & 7) << 3;
  const float tnext = scal->t;   // stage-1 time = t (c=0)

  for (int idx = tid; idx < 1024; idx += 256) {
    int m = idx >> 4, c4 = (idx & 15) << 2;
    int g = (b * 64 + ty0 + (m >> 3)) * 64 + tx0 + (m & 7);
    float4 v;
    if (acc) { v = *(const float4*)&y5[(size_t)g * 64 + c4]; *(float4*)&y[(size_t)g * 64 + c4] = v; }
    else     { v = *(const float4*)&y[(size_t)g * 64 + c4]; }
    unsigned short ha, hb, hc, hd, la, lb, lc, ld;
    split2(v.x, ha, la); split2(v.y, hb, lb); split2(v.z, hc, lc); split2(v.w, hd, ld);
    short4 hv; hv.x = (short)ha; hv.y = (short)hb; hv.z = (short)hc; hv.w = (short)hd;
    short4 lv; lv.x = (short)la; lv.y = (short)lb; lv.z = (short)lc; lv.w = (short)ld;
    *(short4*)&u_hi[m * 72 + c4] = hv;
    *(short4*)&u_lo[m * 72 + c4] = lv;
  }
  if (done) return;   // uniform: final-accept update only

  const int w = tid >> 6, lane = tid & 63, quad = lane >> 4, nl = lane & 15;
  const f32x4 z4 = {0.f, 0.f, 0.f, 0.f};
  f32x4 accf[8];
  for (int nt = 0; nt < 8; nt++) accf[nt] = z4;
  const int mC = w * 16 + nl;
  for (int kc = 0; kc < 2; kc++) {
    __syncthreads();
    #pragma unroll
    for (int u = 0; u < 4; u++)
      ((int4*)w1ch)[tid + u * 256] = ((const int4*)(Wm1 + kc * 8192))[tid + u * 256];
    __syncthreads();
    frag8 Ah = *(const frag8*)&u_hi[mC * 72 + kc * 32 + quad * 8];
    frag8 Al = *(const frag8*)&u_lo[mC * 72 + kc * 32 + quad * 8];
    #pragma unroll
    for (int nt = 0; nt < 8; nt++) {
      frag8 Bh = *(const frag8*)&w1ch[(nt * 2) * 512 + lane * 8];
      frag8 Bl = *(const frag8*)&w1ch[(nt * 2 + 1) * 512 + lane * 8];
      accf[nt] = __builtin_amdgcn_mfma_f32_16x16x32_bf16(Ah, Bh, accf[nt], 0, 0, 0);
      accf[nt] = __builtin_amdgcn_mfma_f32_16x16x32_bf16(Al, Bh, accf[nt], 0, 0, 0);
      accf[nt] = __builtin_amdgcn_mfma_f32_16x16x32_bf16(Ah, Bl, accf[nt], 0, 0, 0);
      accf[nt] = __builtin_amdgcn_mfma_f32_16x16x32_bf16(Al, Bl, accf[nt], 0, 0, 0);
    }
  }
  const float* b1p = wbuf + 8320;
  const float* wt1 = wbuf;
  for (int nt = 0; nt < 8; nt++) {
    int cout = nt * 16 + nl;
    float bb = b1p[cout] + tnext * wt1[cout];
    #pragma unroll
    for (int r = 0; r < 4; r++) {
      int m = w * 16 + quad * 4 + r;
      int g = (b * 64 + ty0 + (m >> 3)) * 64 + tx0 + (m & 7);
      h1out[(size_t)g * 128 + cout] = fmaxf(accf[nt][r] + bb, 0.f);
    }
  }
}

// ---- fused RK-stage kernel: conv3 -> conv1b -> (K,axpy|y5|err) -> conv1f ----
template<int NKR, bool WRITE_K, bool DO_Y5, bool DO_ERR, bool DO_CONV1>
__global__ __launch_bounds__(256) void stage_kernel(Scal* __restrict__ scal,
    float tcur_c, float tnext_c,
    const float* __restrict__ h1in, float* __restrict__ h1out,
    const float* __restrict__ y, float* __restrict__ y5,
    const float* __restrict__ Ka, const float* __restrict__ Kb,
    const float* __restrict__ Kc, const float* __restrict__ Kd,
    const float* __restrict__ Ke,
    float ca, float cb, float cc, float cd, float cf,
    float* __restrict__ Kout,
    const float* __restrict__ wbuf, const unsigned short* __restrict__ Wm2,
    const unsigned short* __restrict__ Wm3, const unsigned short* __restrict__ Wm1) {
  if (scal->done) return;
  __shared__ __align__(16) char uni[45184];
  const int tid = threadIdx.x;
  const int b = blockIdx.x >> 6, tile = blockIdx.x & 63;
  const int ty0 = (tile >> 3) << 3, tx0 = (tile & 7) << 3;
  const float hs = scal->hs;
  const float tcur = scal->t + tcur_c * hs;
  const float tnext = scal->t + tnext_c * hs;
  const int w = tid >> 6, lane = tid & 63, quad = lane >> 4, nl = lane & 15;

  // ================= Phase A: conv3x3 SAME 129->128 relu (R3-proven core) ====
  unsigned short* t_hi = (unsigned short*)uni;        // 100*72
  unsigned short* t_lo = t_hi + 7200;
  unsigned short* wch  = t_lo + 7200;                 // 8192
  const int pxw3 = (w & 1) * 32, ntb3 = (w >> 1) * 4;
  const int m0 = pxw3 + nl, m1 = m0 + 16;
  const int pos0 = (m0 >> 3) * 10 + (m0 & 7);
  const int pos1 = (m1 >> 3) * 10 + (m1 & 7);
  const f32x4 z4 = {0.f, 0.f, 0.f, 0.f};
  f32x4 acc3[2][4];
  for (int mt = 0; mt < 2; mt++) for (int nt = 0; nt < 4; nt++) acc3[mt][nt] = z4;

  for (int ch = 0; ch < 2; ch++) {
    __syncthreads();
    for (int idx = tid; idx < 1600; idx += 256) {
      int pos = idx >> 4, c4 = (idx & 15) << 2;
      int iy = pos / 10, ix = pos - iy * 10;
      int gy = ty0 + iy - 1, gx = tx0 + ix - 1;
      float4 v = make_float4(0.f, 0.f, 0.f, 0.f);
      if (gy >= 0 && gy < 64 && gx >= 0 && gx < 64)
        v = *(const float4*)&h1in[(size_t)((b * 64 + gy) * 64 + gx) * 128 + ch * 64 + c4];
      unsigned short ha, hb, hc, hd, la, lb, lc, ld;
      split2(v.x, ha, la); split2(v.y, hb, lb); split2(v.z, hc, lc); split2(v.w, hd, ld);
      short4 hv; hv.x = (short)ha; hv.y = (short)hb; hv.z = (short)hc; hv.w = (short)hd;
      short4 lv; lv.x = (short)la; lv.y = (short)lb; lv.z = (short)lc; lv.w = (short)ld;
      *(short4*)&t_hi[pos * 72 + c4] = hv;
      *(short4*)&t_lo[pos * 72 + c4] = lv;
    }
    for (int ky = 0; ky < 3; ky++) {
      for (int kx = 0; kx < 3; kx++) {
        const int tap = ky * 3 + kx;
        const int a0 = (pos0 + ky * 10 + kx) * 72 + quad * 8;
        const int a1 = (pos1 + ky * 10 + kx) * 72 + quad * 8;
        for (int kc2 = 0; kc2 < 2; kc2++) {
          __syncthreads();
          const int4* wsrc = (const int4*)(Wm2 + (size_t)(tap * 4 + ch * 2 + kc2) * 8192);
          ((int4*)wch)[tid]       = wsrc[tid];
          ((int4*)wch)[tid + 256] = wsrc[tid + 256];
          ((int4*)wch)[tid + 512] = wsrc[tid + 512];
          ((int4*)wch)[tid + 768] = wsrc[tid + 768];
          __syncthreads();
          frag8 Ah0 = *(const frag8*)&t_hi[a0 + kc2 * 32];
          frag8 Al0 = *(const frag8*)&t_lo[a0 + kc2 * 32];
          frag8 Ah1 = *(const frag8*)&t_hi[a1 + kc2 * 32];
          frag8 Al1 = *(const frag8*)&t_lo[a1 + kc2 * 32];
          #pragma unroll
          for (int nt = 0; nt < 4; nt++) {
            frag8 Bh = *(const frag8*)&wch[((ntb3 + nt) * 2    ) * 512 + lane * 8];
            frag8 Bl = *(const frag8*)&wch[((ntb3 + nt) * 2 + 1) * 512 + lane * 8];
            acc3[0][nt] = __builtin_amdgcn_mfma_f32_16x16x32_bf16(Ah0, Bh, acc3[0][nt], 0, 0, 0);
            acc3[0][nt] = __builtin_amdgcn_mfma_f32_16x16x32_bf16(Al0, Bh, acc3[0][nt], 0, 0, 0);
            acc3[0][nt] = __builtin_amdgcn_mfma_f32_16x16x32_bf16(Ah0, Bl, acc3[0][nt], 0, 0, 0);
            acc3[0][nt] = __builtin_amdgcn_mfma_f32_16x16x32_bf16(Al0, Bl, acc3[0][nt], 0, 0, 0);
            acc3[1][nt] = __builtin_amdgcn_mfma_f32_16x16x32_bf16(Ah1, Bh, acc3[1][nt], 0, 0, 0);
            acc3[1][nt] = __builtin_amdgcn_mfma_f32_16x16x32_bf16(Al1, Bh, acc3[1][nt], 0, 0, 0);
            acc3[1][nt] = __builtin_amdgcn_mfma_f32_16x16x32_bf16(Ah1, Bl, acc3[1][nt], 0, 0, 0);
            acc3[1][nt] = __builtin_amdgcn_mfma_f32_16x16x32_bf16(Al1, Bl, acc3[1][nt], 0, 0, 0);
          }
        }
      }
    }
  }

  // epilogue -> h2 in LDS (overlays t_*; all LDS reads done)
  __syncthreads();
  unsigned short* h2_hi = (unsigned short*)uni;        // 64*136
  unsigned short* h2_lo = h2_hi + 8704;
  {
    const float* b2p = wbuf + 157056;
    const float* w2t = wbuf + 8448;
    for (int nt = 0; nt < 4; nt++) {
      int cout = (ntb3 + nt) * 16 + nl;
      float bb = b2p[cout];
      float wt[9];
      #pragma unroll
      for (int tap = 0; tap < 9; tap++) wt[tap] = w2t[tap * 16512 + cout];
      #pragma unroll
      for (int mt = 0; mt < 2; mt++) {
        #pragma unroll
        for (int r = 0; r < 4; r++) {
          int m = pxw3 + mt * 16 + quad * 4 + r;
          int oy = ty0 + (m >> 3), ox = tx0 + (m & 7);
          float tadd = 0.f;
          #pragma unroll
          for (int ky = 0; ky < 3; ky++) {
            int iy = oy + ky - 1;
            bool yok = (iy >= 0 && iy < 64);
            #pragma unroll
            for (int kx = 0; kx < 3; kx++) {
              int ix = ox + kx - 1;
              if (yok && ix >= 0 && ix < 64) tadd += wt[ky * 3 + kx];
            }
          }
          float v = fmaxf(acc3[mt][nt][r] + bb + tcur * tadd, 0.f);
          unsigned short hh, ll; split2(v, hh, ll);
          h2_hi[m * 136 + cout] = hh;
          h2_lo[m * 136 + cout] = ll;
        }
      }
    }
  }

  // ================= Phase B: conv1b 129->64 (MFMA) ==========================
  unsigned short* w3ch = (unsigned short*)(uni + 34816);  // 4096 us per kc chunk
  f32x4 accb[4];
  for (int nt = 0; nt < 4; nt++) accb[nt] = z4;
  const int mB = w * 16 + nl;
  for (int kc = 0; kc < 4; kc++) {
    __syncthreads();   // first iter: h2 visible; later: protect w3ch reads
    const int4* wsrc = (const int4*)(Wm3 + kc * 4096);
    ((int4*)w3ch)[tid] = wsrc[tid];
    ((int4*)w3ch)[tid + 256] = wsrc[tid + 256];
    __syncthreads();
    frag8 Ah = *(const frag8*)&h2_hi[mB * 136 + kc * 32 + quad * 8];
    frag8 Al = *(const frag8*)&h2_lo[mB * 136 + kc * 32 + quad * 8];
    #pragma unroll
    for (int nt = 0; nt < 4; nt++) {
      frag8 Bh = *(const frag8*)&w3ch[(nt * 2) * 512 + lane * 8];
      frag8 Bl = *(const frag8*)&w3ch[(nt * 2 + 1) * 512 + lane * 8];
      accb[nt] = __builtin_amdgcn_mfma_f32_16x16x32_bf16(Ah, Bh, accb[nt], 0, 0, 0);
      accb[nt] = __builtin_amdgcn_mfma_f32_16x16x32_bf16(Al, Bh, accb[nt], 0, 0, 0);
      accb[nt] = __builtin_amdgcn_mfma_f32_16x16x32_bf16(Ah, Bl, accb[nt], 0, 0, 0);
      accb[nt] = __builtin_amdgcn_mfma_f32_16x16x32_bf16(Al, Bl, accb[nt], 0, 0, 0);
    }
  }

  // phase B epilogue: K_s values + axpy / y5 / err
  const float* b3p = wbuf + 165440;
  const float* wt3 = wbuf + 157184;
  int gp[4];
  #pragma unroll
  for (int r = 0; r < 4; r++) {
    int m = w * 16 + quad * 4 + r;
    gp[r] = (b * 64 + ty0 + (m >> 3)) * 64 + tx0 + (m & 7);
  }
  float kf[4][4];
  for (int nt = 0; nt < 4; nt++) {
    int cout = nt * 16 + nl;
    float bb = b3p[cout] + tcur * wt3[cout];
    #pragma unroll
    for (int r = 0; r < 4; r++) kf[nt][r] = accb[nt][r] + bb;
    if constexpr (WRITE_K) {
      #pragma unroll
      for (int r = 0; r < 4; r++) Kout[(size_t)gp[r] * 64 + cout] = kf[nt][r];
    }
  }

  if constexpr (DO_ERR) {
    const float E1 = (float)(71.0/57600.0),  E3 = (float)(-71.0/16695.0);
    const float E4 = (float)(71.0/1920.0),   E5 = (float)(-17253.0/339200.0);
    const float E6 = (float)(22.0/525.0),    E7 = (float)(-1.0/40.0);
    double local = 0.0;
    for (int nt = 0; nt < 4; nt++) {
      int cout = nt * 16 + nl;
      #pragma unroll
      for (int r = 0; r < 4; r++) {
        size_t gi = (size_t)gp[r] * 64 + cout;
        float s1 = Ka[gi], s3 = Kb[gi], s4 = Kc[gi], s5 = Kd[gi], s6 = Ke[gi];
        float s7 = kf[nt][r];
        float er = hs * (E1*s1 + E3*s3 + E4*s4 + E5*s5 + E6*s6 + E7*s7);
        float yv = y[gi], y5v = y5[gi];
        float sc = 1e-3f + 1e-3f * fmaxf(fabsf(yv), fabsf(y5v));
        float rr = er / sc;
        local += (double)(rr * rr);
      }
    }
    for (int off = 32; off > 0; off >>= 1) local += __shfl_down(local, off);
    __syncthreads();
    double* wsum = (double*)uni;
    if (lane == 0) wsum[w] = local;
    __syncthreads();
    if (tid == 0)
      atomicAdd(&scal->errsum, wsum[0] + wsum[1] + wsum[2] + wsum[3]);
    return;
  }

  // axpy: u = y + hs*(ca*Ka + ... + cf*Kfresh), fresh coefficient LAST
  float uu[4][4];
  for (int nt = 0; nt < 4; nt++) {
    int cout = nt * 16 + nl;
    #pragma unroll
    for (int r = 0; r < 4; r++) {
      size_t gi = (size_t)gp[r] * 64 + cout;
      float s;
      if constexpr (NKR == 0) { s = cf * kf[nt][r]; }
      else {
        s = ca * Ka[gi];
        if constexpr (NKR > 1) s += cb * Kb[gi];
        if constexpr (NKR > 2) s += cc * Kc[gi];
        if constexpr (NKR > 3) s += cd * Kd[gi];
        s += cf * kf[nt][r];
      }
      float u = y[gi] + hs * s;
      uu[nt][r] = u;
      if constexpr (DO_Y5) y5[gi] = u;
    }
  }

  if constexpr (DO_CONV1) {
    __syncthreads();   // all phase-B LDS reads done before overlaying with u
    unsigned short* u_hi = (unsigned short*)uni;        // 64*72
    unsigned short* u_lo = u_hi + 4608;
    unsigned short* w1ch = (unsigned short*)(uni + 18432);
    for (int nt = 0; nt < 4; nt++) {
      #pragma unroll
      for (int r = 0; r < 4; r++) {
        int m = w * 16 + quad * 4 + r;
        int a = m * 72 + nt * 16 + nl;
        unsigned short hh, ll; split2(uu[nt][r], hh, ll);
        u_hi[a] = hh; u_lo[a] = ll;
      }
    }
    f32x4 accf[8];
    for (int nt = 0; nt < 8; nt++) accf[nt] = z4;
    const int mC = w * 16 + nl;
    for (int kc = 0; kc < 2; kc++) {
      __syncthreads();
      #pragma unroll
      for (int u = 0; u < 4; u++)
        ((int4*)w1ch)[tid + u * 256] = ((const int4*)(Wm1 + kc * 8192))[tid + u * 256];
      __syncthreads();
      frag8 Ah = *(const frag8*)&u_hi[mC * 72 + kc * 32 + quad * 8];
      frag8 Al = *(const frag8*)&u_lo[mC * 72 + kc * 32 + quad * 8];
      #pragma unroll
      for (int nt = 0; nt < 8; nt++) {
        frag8 Bh = *(const frag8*)&w1ch[(nt * 2) * 512 + lane * 8];
        frag8 Bl = *(const frag8*)&w1ch[(nt * 2 + 1) * 512 + lane * 8];
        accf[nt] = __builtin_amdgcn_mfma_f32_16x16x32_bf16(Ah, Bh, accf[nt], 0, 0, 0);
        accf[nt] = __builtin_amdgcn_mfma_f32_16x16x32_bf16(Al, Bh, accf[nt], 0, 0, 0);
        accf[nt] = __builtin_amdgcn_mfma_f32_16x16x32_bf16(Ah, Bl, accf[nt], 0, 0, 0);
        accf[nt] = __builtin_amdgcn_mfma_f32_16x16x32_bf16(Al, Bl, accf[nt], 0, 0, 0);
      }
    }
    const float* b1p = wbuf + 8320;
    const float* wt1 = wbuf;
    for (int nt = 0; nt < 8; nt++) {
      int cout = nt * 16 + nl;
      float bb = b1p[cout] + tnext * wt1[cout];
      #pragma unroll
      for (int r = 0; r < 4; r++) {
        int m = w * 16 + quad * 4 + r;
        int g = (b * 64 + ty0 + (m >> 3)) * 64 + tx0 + (m & 7);
        h1out[(size_t)g * 128 + cout] = fmaxf(accf[nt][r] + bb, 0.f);
      }
    }
  }
}

// ---- output head: 1x1 conv 64 -> 10, with final y/y5 select -----------------
__global__ __launch_bounds__(256) void head_kernel(const Scal* __restrict__ scal,
    const float* __restrict__ y, const float* __restrict__ y5,
    const float* __restrict__ wo, const float* __restrict__ bo,
    void* __restrict__ out) {
  __shared__ float w_lds[640];
  __shared__ float b_lds[10];
  int tid = threadIdx.x;
  for (int i = tid; i < 640; i += 256) w_lds[i] = wo[i];
  if (tid < 10) b_lds[tid] = bo[tid];
  __syncthreads();
  const int acc_f = scal->accept;
  int pix = blockIdx.x * 256 + tid;
  const float4* yv = (const float4*)((acc_f ? y5 : y) + (size_t)pix * 64);
  float acc[10];
  #pragma unroll
  for (int o = 0; o < 10; o++) acc[o] = b_lds[o];
  for (int k4 = 0; k4 < 16; k4++) {
    float4 v = yv[k4];
    #pragma unroll
    for (int j = 0; j < 4; j++) {
      float a = ((const float*)&v)[j];
      int k = k4 * 4 + j;
      #pragma unroll
      for (int o = 0; o < 10; o++) acc[o] += a * w_lds[k * 10 + o];
    }
  }
  if (scal->is_bf16) {
    unsigned short* o16 = (unsigned short*)out;
    #pragma unroll
    for (int o = 0; o < 10; o++) o16[(size_t)pix * 10 + o] = f2bf(acc[o]);
  } else {
    float* of = (float*)out;
    #pragma unroll
    for (int o = 0; o < 10; o++) of[(size_t)pix * 10 + o] = acc[o];
  }
}

extern "C" void kernel_launch(void* const* d_in, const int* in_sizes, int n_in,
                              void* d_out, int out_size, void* d_ws, size_t ws_size,
                              hipStream_t stream) {
  (void)in_sizes; (void)n_in; (void)out_size; (void)ws_size;
  char* wsb = (char*)d_ws;
  Scal* scal = (Scal*)wsb;
  float* base = (float*)(wsb + 256);
  float* y  = base;
  float* K0 = base + (size_t)NYF * 1;
  float* K1 = base + (size_t)NYF * 2;
  float* K2 = base + (size_t)NYF * 3;
  float* K3 = base + (size_t)NYF * 4;
  float* K4 = base + (size_t)NYF * 5;
  float* K5 = base + (size_t)NYF * 6;
  float* y5 = base + (size_t)NYF * 7;
  float* hA = base + (size_t)NYF * 8;    // [32768][128] fp32
  float* hB = base + (size_t)NYF * 10;
  float* wbuf = base + (size_t)NYF * 12; // 166154 floats (pad 166400)
  unsigned short* Wm1 = (unsigned short*)(wbuf + 166400);  // 16384
  unsigned short* Wm2 = Wm1 + 16384;                       // 294912
  unsigned short* Wm3 = Wm2 + 294912;                      // 16384

  const float cA21 = (float)(1.0/5.0);
  const float cA31 = (float)(3.0/40.0),       cA32 = (float)(9.0/40.0);
  const float cA41 = (float)(44.0/45.0),      cA42 = (float)(-56.0/15.0),    cA43 = (float)(32.0/9.0);
  const float cA51 = (float)(19372.0/6561.0), cA52 = (float)(-25360.0/2187.0);
  const float cA53 = (float)(64448.0/6561.0), cA54 = (float)(-212.0/729.0);
  const float cA61 = (float)(9017.0/3168.0),  cA62 = (float)(-355.0/33.0);
  const float cA63 = (float)(46732.0/5247.0), cA64 = (float)(49.0/176.0),    cA65 = (float)(-5103.0/18656.0);
  const float cB1 = (float)(35.0/384.0),  cB3 = (float)(500.0/1113.0), cB4 = (float)(125.0/192.0);
  const float cB5 = (float)(-2187.0/6784.0), cB6 = (float)(11.0/84.0);
  const float cC2 = 0.2f, cC3 = 0.3f, cC4 = 0.8f, cC5 = (float)(8.0/9.0);

  detect_kernel<<<1, 64, 0, stream>>>(scal, d_in[0]);
  convert_x_kernel<<<NYF / 1024, 256, 0, stream>>>(scal, d_in[0], y);
  convert_w_kernel<<<(166154 + 255) / 256, 256, 0, stream>>>(scal,
      d_in[1], d_in[2], d_in[3], d_in[4], d_in[5], d_in[6], d_in[7], d_in[8], wbuf);
  pack_all_kernel<<<640, 256, 0, stream>>>(wbuf, Wm1, Wm2, Wm3);

  for (int it = 0; it < 32; it++) {
    kfirst_kernel<<<512, 256, 0, stream>>>(scal, y5, y, wbuf, Wm1, hA);
    // A0: conv3/conv1b at c=0 -> K0; u2 = y + hs*a21*K0; conv1f at c2
    stage_kernel<0, true, false, false, true><<<512, 256, 0, stream>>>(scal, 0.f, cC2,
        hA, hB, y, y5, y, y, y, y, y, 0, 0, 0, 0, cA21, K0, wbuf, Wm2, Wm3, Wm1);
    // A1 -> K1; u3 = y + hs*(a31 K0 + a32 K1); conv1f at c3
    stage_kernel<1, true, false, false, true><<<512, 256, 0, stream>>>(scal, cC2, cC3,
        hB, hA, y, y5, K0, y, y, y, y, cA31, 0, 0, 0, cA32, K1, wbuf, Wm2, Wm3, Wm1);
    // A2 -> K2; u4 = y + hs*(a41 K0 + a42 K1 + a43 K2); conv1f at c4
    stage_kernel<2, true, false, false, true><<<512, 256, 0, stream>>>(scal, cC3, cC4,
        hA, hB, y, y5, K0, K1, y, y, y, cA41, cA42, 0, 0, cA43, K2, wbuf, Wm2, Wm3, Wm1);
    // A3 -> K3; u5; conv1f at c5
    stage_kernel<3, true, false, false, true><<<512, 256, 0, stream>>>(scal, cC4, cC5,
        hB, hA, y, y5, K0, K1, K2, y, y, cA51, cA52, cA53, 0, cA54, K3, wbuf, Wm2, Wm3, Wm1);
    // A4 -> K4; u6; conv1f at c=1
    stage_kernel<4, true, false, false, true><<<512, 256, 0, stream>>>(scal, cC5, 1.f,
        hA, hB, y, y5, K0, K1, K2, K3, y, cA61, cA62, cA63, cA64, cA65, K4, wbuf, Wm2, Wm3, Wm1);
    // A5 -> K5; y5 = y + hs*(B1 K0 + B3 K2 + B4 K3 + B5 K4 + B6 K5); conv1f(y5) at c=1
    stage_kernel<4, true, true, false, true><<<512, 256, 0, stream>>>(scal, 1.f, 1.f,
        hB, hA, y, y5, K0, K2, K3, K4, y, cB1, cB3, cB4, cB5, cB6, K5, wbuf, Wm2, Wm3, Wm1);
    // A6: k7 + fused error norm
    stage_kernel<0, false, false, true, false><<<512, 256, 0, stream>>>(scal, 1.f, 1.f,
        hA, hB, y, y5, K0, K2, K3, K4, K5, 0, 0, 0, 0, 0, K5, wbuf, Wm2, Wm3, Wm1);
    accept_kernel<<<1, 1, 0, stream>>>(scal);
  }
  head_kernel<<<NPIXT / 256, 256, 0, stream>>>(scal, y, y5, wbuf + 165504, wbuf + 166144, d_out);
}